// Round 18
// baseline (258.271 us; speedup 1.0000x reference)
//
#include <hip/hip_runtime.h>

constexpr int N_ROWS = 131072;
constexpr int DIM    = 512;
constexpr int KP     = 512;
constexpr int BM     = 128;       // rows per block (8 autonomous waves x 16)
constexpr int NST    = 64;        // 64 stages of 4 KB (8 col-chunks x 8 k-chunks)

constexpr float PSCALE = 131072.0f;            // 2^17: P -> fp8 normal range
constexpr float DFACT  = 1.52587890625e-5f;    // 2 / 2^17

typedef float     f32x4 __attribute__((ext_vector_type(4)));
typedef long long ll2   __attribute__((ext_vector_type(2)));

__device__ inline unsigned cvtpk_fp8(float a, float b) {
    unsigned r = 0;   // "+v": high 16 bits preserved (= 0)
    asm volatile("v_cvt_pk_fp8_f32 %0, %1, %2" : "+v"(r) : "v"(a), "v"(b));
    return r;
}
__device__ inline void gload_lds16(const unsigned char* g, unsigned char* l) {
    // LDS dest must be WAVE-UNIFORM; HW adds lane*16.
    __builtin_amdgcn_global_load_lds(
        (const __attribute__((address_space(1))) unsigned*)g,
        (__attribute__((address_space(3))) unsigned*)l, 16, 0, 0);
}

// ---------------------------------------------------------------------------
// prep: pn[c] = ||P[c]||^2 (fp32, unscaled); Pq = fp8(P * 2^17) in 4 KB stage
// blocks (cc = c/64, kq = k/64): octet (c, l=k/8): kk=l>>2, g=l&3, kq=kk>>1,
// e=kk&1, col=c&63 -> byte (cc*8+kq)*4096 + g*1024 + col*16 + e*8.
// One ds_read_b128 at (g,col) then feeds MFMA k-steps kq*2 and kq*2+1.
// ---------------------------------------------------------------------------
__global__ void prep_kernel(const float* __restrict__ P, float* __restrict__ pn,
                            unsigned char* __restrict__ Pq) {
    const int c = blockIdx.x, l = threadIdx.x;   // l = k-octet 0..63
    const float* row = P + (size_t)c * DIM;
    float4 a = *reinterpret_cast<const float4*>(row + l * 8);
    float4 b = *reinterpret_cast<const float4*>(row + l * 8 + 4);
    float s = a.x*a.x + a.y*a.y + a.z*a.z + a.w*a.w
            + b.x*b.x + b.y*b.y + b.z*b.z + b.w*b.w;
    unsigned lo = cvtpk_fp8(a.x * PSCALE, a.y * PSCALE)
                | (cvtpk_fp8(a.z * PSCALE, a.w * PSCALE) << 16);
    unsigned hi = cvtpk_fp8(b.x * PSCALE, b.y * PSCALE)
                | (cvtpk_fp8(b.z * PSCALE, b.w * PSCALE) << 16);
    unsigned long long v = (unsigned long long)lo | ((unsigned long long)hi << 32);
    const int kk = l >> 2, g = l & 3, kq = kk >> 1, e = kk & 1;
    const int cc = c >> 6, col = c & 63;
    const size_t off =
        (size_t)(cc * 8 + kq) * 4096 + (size_t)g * 1024 + col * 16 + e * 8;
    *reinterpret_cast<unsigned long long*>(Pq + off) = v;
#pragma unroll
    for (int o = 32; o > 0; o >>= 1) s += __shfl_down(s, o);
    if (l == 0) pn[c] = s;
}

// ---------------------------------------------------------------------------
// vq: BARRIER-FREE main loop. 8 autonomous waves x 16 rows; A = fp8(X) full
// K=512 in 16 named i64 regs. Each wave streams B through its PRIVATE 8 KB
// LDS slice (2 x 4 KB dbuf) via global_load_lds, self-paced with per-wave
// counted vmcnt(4). 64 stages; per stage 4 ds_read_b128 + 8 MFMA on 4
// independent acc chains; fold every 8 stages. Argmin, loss, gather all
// wave-private. One __syncthreads total (pn_s staging).
// ---------------------------------------------------------------------------
__global__ __launch_bounds__(512, 2)
void vq_kernel(const float* __restrict__ X, const float* __restrict__ P,
               const unsigned char* __restrict__ Pq, const float* __restrict__ pn,
               float* __restrict__ out, double* __restrict__ lsum) {
    __shared__ __align__(16) unsigned char Bs[8][8192];  // per-wave slices
    __shared__ float pn_s[KP];
    __shared__ int   idx_s[BM];

    const int tid  = threadIdx.x;
    const int lane = tid & 63;
    const int wid  = tid >> 6;    // 0..7
    const int lr   = lane & 15;   // A row-in-wave / B col-in-tile
    const int lg   = lane >> 4;   // k-subgroup
    const size_t row0 = (size_t)blockIdx.x * BM;

    pn_s[tid] = pn[tid];          // 512 threads -> all 512 entries
    __syncthreads();              // the ONLY block barrier

    unsigned char* slice = Bs[wid];

    auto STAGE = [&](int s, int buf) {
        const unsigned char* src = Pq + (size_t)s * 4096 + lane * 16;
        unsigned char* dstu = slice + buf * 4096;   // wave-uniform base
#pragma unroll
        for (int i = 0; i < 4; ++i)
            gload_lds16(src + i * 1024, dstu + i * 1024);
    };

    STAGE(0, 0);   // prefetch; latency hides under A-load

    // ---- A: X -> fp8 in 16 NAMED i64 regs + ||x||^2 (fp32) ----
    float xsq = 0.f;
    const float* xb = X + (row0 + wid * 16 + lr) * DIM + lg * 8;

#define ALOAD(KK, areg)                                                        \
    long long areg;                                                            \
    {                                                                          \
        float4 v0 = *reinterpret_cast<const float4*>(xb + (KK) * 32);          \
        float4 v1 = *reinterpret_cast<const float4*>(xb + (KK) * 32 + 4);      \
        xsq += v0.x*v0.x + v0.y*v0.y + v0.z*v0.z + v0.w*v0.w                   \
             + v1.x*v1.x + v1.y*v1.y + v1.z*v1.z + v1.w*v1.w;                  \
        unsigned lo = cvtpk_fp8(v0.x, v0.y) | (cvtpk_fp8(v0.z, v0.w) << 16);   \
        unsigned hi = cvtpk_fp8(v1.x, v1.y) | (cvtpk_fp8(v1.z, v1.w) << 16);   \
        areg = (long long)((unsigned long long)lo |                            \
                           ((unsigned long long)hi << 32));                    \
    }
    ALOAD(0,  a0)  ALOAD(1,  a1)  ALOAD(2,  a2)  ALOAD(3,  a3)
    ALOAD(4,  a4)  ALOAD(5,  a5)  ALOAD(6,  a6)  ALOAD(7,  a7)
    ALOAD(8,  a8)  ALOAD(9,  a9)  ALOAD(10, a10) ALOAD(11, a11)
    ALOAD(12, a12) ALOAD(13, a13) ALOAD(14, a14) ALOAD(15, a15)
#undef ALOAD

    float bv0 = 3.4e38f, bv1 = 3.4e38f, bv2 = 3.4e38f, bv3 = 3.4e38f;
    int   bi0 = 0, bi1 = 0, bi2 = 0, bi3 = 0;
    f32x4 acc0 = {0.f, 0.f, 0.f, 0.f}, acc1 = {0.f, 0.f, 0.f, 0.f};
    f32x4 acc2 = {0.f, 0.f, 0.f, 0.f}, acc3 = {0.f, 0.f, 0.f, 0.f};

// One 4 KB stage: pin order | issue next stage | wait own 4 loads | 4 b128
// reads + 8 MFMA (4 independent chains). All waits are per-wave.
#define KSTEP(KQ, aE, aO)                                                      \
    {                                                                          \
        __builtin_amdgcn_sched_barrier(0);                                     \
        const int ns = cc * 8 + (KQ) + 1;                                      \
        if (ns < NST) {                                                        \
            STAGE(ns, ((KQ) + 1) & 1);                                         \
            asm volatile("s_waitcnt vmcnt(4)" ::: "memory");                   \
        } else {                                                               \
            asm volatile("s_waitcnt vmcnt(0)" ::: "memory");                   \
        }                                                                      \
        const unsigned char* bb = slice + ((KQ) & 1) * 4096                    \
                                + lg * 1024 + lr * 16;                         \
        ll2 q0 = *reinterpret_cast<const ll2*>(bb);                            \
        ll2 q1 = *reinterpret_cast<const ll2*>(bb + 256);                      \
        ll2 q2 = *reinterpret_cast<const ll2*>(bb + 512);                      \
        ll2 q3 = *reinterpret_cast<const ll2*>(bb + 768);                      \
        acc0 = __builtin_amdgcn_mfma_f32_16x16x32_fp8_fp8(aE, q0[0], acc0, 0, 0, 0); \
        acc1 = __builtin_amdgcn_mfma_f32_16x16x32_fp8_fp8(aE, q1[0], acc1, 0, 0, 0); \
        acc2 = __builtin_amdgcn_mfma_f32_16x16x32_fp8_fp8(aE, q2[0], acc2, 0, 0, 0); \
        acc3 = __builtin_amdgcn_mfma_f32_16x16x32_fp8_fp8(aE, q3[0], acc3, 0, 0, 0); \
        acc0 = __builtin_amdgcn_mfma_f32_16x16x32_fp8_fp8(aO, q0[1], acc0, 0, 0, 0); \
        acc1 = __builtin_amdgcn_mfma_f32_16x16x32_fp8_fp8(aO, q1[1], acc1, 0, 0, 0); \
        acc2 = __builtin_amdgcn_mfma_f32_16x16x32_fp8_fp8(aO, q2[1], acc2, 0, 0, 0); \
        acc3 = __builtin_amdgcn_mfma_f32_16x16x32_fp8_fp8(aO, q3[1], acc3, 0, 0, 0); \
    }

#define FOLD_CT(accv, CT)                                                      \
    {                                                                          \
        const float pnv = pn_s[cc * 64 + (CT) * 16 + lr];                      \
        const int   ci  = cc * 64 + (CT) * 16 + lr;                            \
        float d;                                                               \
        d = fmaf(-DFACT, accv[0], pnv);                                        \
        if (d < bv0) { bv0 = d; bi0 = ci; }                                    \
        d = fmaf(-DFACT, accv[1], pnv);                                        \
        if (d < bv1) { bv1 = d; bi1 = ci; }                                    \
        d = fmaf(-DFACT, accv[2], pnv);                                        \
        if (d < bv2) { bv2 = d; bi2 = ci; }                                    \
        d = fmaf(-DFACT, accv[3], pnv);                                        \
        if (d < bv3) { bv3 = d; bi3 = ci; }                                    \
        accv = (f32x4){0.f, 0.f, 0.f, 0.f};                                    \
    }

    for (int cc = 0; cc < 8; ++cc) {    // 64-col chunks
        KSTEP(0, a0,  a1)  KSTEP(1, a2,  a3)
        KSTEP(2, a4,  a5)  KSTEP(3, a6,  a7)
        KSTEP(4, a8,  a9)  KSTEP(5, a10, a11)
        KSTEP(6, a12, a13) KSTEP(7, a14, a15)
        FOLD_CT(acc0, 0) FOLD_CT(acc1, 1) FOLD_CT(acc2, 2) FOLD_CT(acc3, 3)
    }
#undef KSTEP
#undef FOLD_CT

    // ---- wave-private argmin across the 16 col-holding lanes ----
#define MERGE(bv, bi, SLOT)                                                    \
    {                                                                          \
        _Pragma("unroll")                                                      \
        for (int m = 1; m < 16; m <<= 1) {                                     \
            float ov = __shfl_xor(bv, m);                                      \
            int   oi = __shfl_xor(bi, m);                                      \
            if (ov < bv || (ov == bv && oi < bi)) { bv = ov; bi = oi; }        \
        }                                                                      \
        if (lr == 0) idx_s[wid * 16 + lg * 4 + (SLOT)] = bi;                   \
    }
    MERGE(bv0, bi0, 0) MERGE(bv1, bi1, 1) MERGE(bv2, bi2, 2) MERGE(bv3, bi3, 3)
#undef MERGE

    // loss partial (wave-private): best dists (lr==0) + ||x||^2 (all lanes)
    float lcl = xsq + (lr == 0 ? bv0 + bv1 + bv2 + bv3 : 0.f);
#pragma unroll
    for (int o = 32; o > 0; o >>= 1) lcl += __shfl_down(lcl, o);
    if (lane == 0) atomicAdd(lsum, (double)lcl);

    // within-wave LDS visibility for idx_s (no block barrier needed)
    asm volatile("s_waitcnt lgkmcnt(0)" ::: "memory");
    __builtin_amdgcn_sched_barrier(0);

    // ---- wave-private epilogue: out[r] = P[idx[r]] for this wave's 16 rows ----
#pragma unroll 4
    for (int i = 0; i < 32; ++i) {
        int q = lane + i * 64;            // 16 rows x 128 float4 per wave
        int rl = q >> 7, f4 = q & 127;
        int idx = idx_s[wid * 16 + rl];
        float4 pv = *reinterpret_cast<const float4*>(
            P + (size_t)idx * DIM + f4 * 4);
        *reinterpret_cast<float4*>(
            out + (row0 + wid * 16 + rl) * DIM + f4 * 4) = pv;
    }
}

__global__ void finalize_kernel(const double* __restrict__ lsum,
                                float* __restrict__ out_loss) {
    out_loss[0] = (float)(1.25 * lsum[0] / ((double)N_ROWS * (double)DIM));
}

extern "C" void kernel_launch(void* const* d_in, const int* in_sizes, int n_in,
                              void* d_out, int out_size, void* d_ws, size_t ws_size,
                              hipStream_t stream) {
    const float* X = (const float*)d_in[0];
    const float* P = (const float*)d_in[1];
    float* out = (float*)d_out;

    // ws: [0,8) lsum; [256,+2K) pn; [4096,+256K) Pq fp8 (4 KB stage blocks)
    double*        lsum = (double*)d_ws;
    float*         pn   = (float*)((char*)d_ws + 256);
    unsigned char* Pq   = (unsigned char*)d_ws + 4096;

    (void)hipMemsetAsync(d_ws, 0, 64, stream);
    prep_kernel<<<KP, 64, 0, stream>>>(P, pn, Pq);
    vq_kernel<<<N_ROWS / BM, 512, 0, stream>>>(X, P, Pq, pn, out, lsum);
    finalize_kernel<<<1, 1, 0, stream>>>(lsum, out + (size_t)N_ROWS * DIM);
    (void)hipMemcpyAsync(out + (size_t)N_ROWS * DIM + 1, P,
                         (size_t)KP * DIM * sizeof(float),
                         hipMemcpyDeviceToDevice, stream);
}

// Round 20
// 164.298 us; speedup vs baseline: 1.5720x; 1.5720x over previous
//
#include <hip/hip_runtime.h>

constexpr int N_ROWS = 131072;
constexpr int DIM    = 512;
constexpr int KP     = 512;
constexpr int BM     = 128;       // rows per block (8 waves x 16 rows)
constexpr int SC     = 64;        // cols per stage (full K=512 each)
constexpr int NS     = KP / SC;   // 8 stages
// stage = 64 cols x 512 K fp8 = 32 KB; double-buffered = 64 KB LDS

constexpr float PSCALE = 131072.0f;            // 2^17: P -> fp8 normal range
constexpr float DFACT  = 1.52587890625e-5f;    // 2 / 2^17

typedef float     f32x4 __attribute__((ext_vector_type(4)));
typedef long long ll2   __attribute__((ext_vector_type(2)));

__device__ inline unsigned cvtpk_fp8(float a, float b) {
    unsigned r = 0;   // "+v": high 16 bits preserved (= 0)
    asm volatile("v_cvt_pk_fp8_f32 %0, %1, %2" : "+v"(r) : "v"(a), "v"(b));
    return r;
}
__device__ inline void gload_lds16(const unsigned char* g, unsigned char* l) {
    // LDS dest must be WAVE-UNIFORM; HW adds lane*16.
    __builtin_amdgcn_global_load_lds(
        (const __attribute__((address_space(1))) unsigned*)g,
        (__attribute__((address_space(3))) unsigned*)l, 16, 0, 0);
}

// ---------------------------------------------------------------------------
// prep: pn[c] = ||P[c]||^2 (fp32, unscaled); Pq = fp8(P * 2^17) blocked by
// stage s=c/64, PAIRED k-step layout: octet (c, l=k/8) with kk=l>>2, g=l&3,
// p=kk>>1, e=kk&1 lives at byte
//   s*32768 + (p*4 + g)*1024 + (c%64)*16 + e*8.
// One ds_read_b128 per (p,g,col) then feeds MFMAs kk=2p and kk=2p+1.
// ---------------------------------------------------------------------------
__global__ void prep_kernel(const float* __restrict__ P, float* __restrict__ pn,
                            unsigned char* __restrict__ Pq) {
    const int c = blockIdx.x, l = threadIdx.x;   // l = k-octet 0..63
    const float* row = P + (size_t)c * DIM;
    float4 a = *reinterpret_cast<const float4*>(row + l * 8);
    float4 b = *reinterpret_cast<const float4*>(row + l * 8 + 4);
    float s = a.x*a.x + a.y*a.y + a.z*a.z + a.w*a.w
            + b.x*b.x + b.y*b.y + b.z*b.z + b.w*b.w;
    unsigned lo = cvtpk_fp8(a.x * PSCALE, a.y * PSCALE)
                | (cvtpk_fp8(a.z * PSCALE, a.w * PSCALE) << 16);
    unsigned hi = cvtpk_fp8(b.x * PSCALE, b.y * PSCALE)
                | (cvtpk_fp8(b.z * PSCALE, b.w * PSCALE) << 16);
    unsigned long long v = (unsigned long long)lo | ((unsigned long long)hi << 32);
    const int st = c >> 6, cl = c & 63;
    const int kk = l >> 2, g = l & 3, p = kk >> 1, e = kk & 1;
    const size_t off =
        (size_t)st * 32768 + (size_t)(p * 4 + g) * 1024 + cl * 16 + e * 8;
    *reinterpret_cast<unsigned long long*>(Pq + off) = v;
#pragma unroll
    for (int o = 32; o > 0; o >>= 1) s += __shfl_down(s, o);
    if (l == 0) pn[c] = s;
}

// ---------------------------------------------------------------------------
// vq: r17 structure (best measured: 176 us). 8 waves x 16 rows; A = fp8(X),
// full K=512, 16 named i64 regs. 8 stages of {64 cols x full K} (32 KB),
// double-buffered, counted vmcnt(4). B via paired ds_read_b128. No setprio.
// NEW vs r17: nontemporal hints on stream-once traffic (X loads, out stores)
// so L2/L3 stay dedicated to the reused tensors (Pq, P).
// ---------------------------------------------------------------------------
__global__ __launch_bounds__(512, 2)
void vq_kernel(const float* __restrict__ X, const float* __restrict__ P,
               const unsigned char* __restrict__ Pq, const float* __restrict__ pn,
               float* __restrict__ out, double* __restrict__ lsum) {
    __shared__ __align__(16) unsigned char Bs[2][32768];  // 2 x 32 KB
    __shared__ float pn_s[KP];
    __shared__ int   idx_s[BM];
    __shared__ float wls[8];

    const int tid  = threadIdx.x;
    const int lane = tid & 63;
    const int wid  = tid >> 6;    // 0..7
    const int lr   = lane & 15;   // A row-in-wave / B col-in-tile
    const int lg   = lane >> 4;   // k-subgroup
    const size_t row0 = (size_t)blockIdx.x * BM;

    auto STAGE = [&](int s, int buf) {
        // 2048 units / 512 threads = 4 per thread; wave-uniform LDS bases.
        const unsigned char* src = Pq + (size_t)s * 32768 + (wid * 64 + lane) * 16;
        unsigned char* dst = &Bs[buf][(wid * 64) * 16];   // wave-uniform base
#pragma unroll
        for (int i = 0; i < 4; ++i)
            gload_lds16(src + (size_t)i * 8192, dst + (size_t)i * 8192);
    };

    STAGE(0, 0);   // prefetch stage 0; latency hides under A-load

    if (tid < KP) pn_s[tid] = pn[tid];

    // ---- A: X -> fp8 in 16 NAMED i64 regs + ||x||^2 (fp32) ----
    float xsq = 0.f;
    const float* xb = X + (row0 + wid * 16 + lr) * DIM + lg * 8;

#define ALOAD(KK, areg)                                                        \
    long long areg;                                                            \
    {                                                                          \
        f32x4 v0 = __builtin_nontemporal_load(                                 \
            reinterpret_cast<const f32x4*>(xb + (KK) * 32));                   \
        f32x4 v1 = __builtin_nontemporal_load(                                 \
            reinterpret_cast<const f32x4*>(xb + (KK) * 32 + 4));               \
        xsq += v0[0]*v0[0] + v0[1]*v0[1] + v0[2]*v0[2] + v0[3]*v0[3]           \
             + v1[0]*v1[0] + v1[1]*v1[1] + v1[2]*v1[2] + v1[3]*v1[3];          \
        unsigned lo = cvtpk_fp8(v0[0], v0[1]) | (cvtpk_fp8(v0[2], v0[3]) << 16); \
        unsigned hi = cvtpk_fp8(v1[0], v1[1]) | (cvtpk_fp8(v1[2], v1[3]) << 16); \
        areg = (long long)((unsigned long long)lo |                            \
                           ((unsigned long long)hi << 32));                    \
    }
    ALOAD(0,  a0)  ALOAD(1,  a1)  ALOAD(2,  a2)  ALOAD(3,  a3)
    ALOAD(4,  a4)  ALOAD(5,  a5)  ALOAD(6,  a6)  ALOAD(7,  a7)
    ALOAD(8,  a8)  ALOAD(9,  a9)  ALOAD(10, a10) ALOAD(11, a11)
    ALOAD(12, a12) ALOAD(13, a13) ALOAD(14, a14) ALOAD(15, a15)
#undef ALOAD

    float bv0 = 3.4e38f, bv1 = 3.4e38f, bv2 = 3.4e38f, bv3 = 3.4e38f;
    int   bi0 = 0, bi1 = 0, bi2 = 0, bi3 = 0;
    f32x4 acc0 = {0.f, 0.f, 0.f, 0.f}, acc1 = {0.f, 0.f, 0.f, 0.f};
    f32x4 acc2 = {0.f, 0.f, 0.f, 0.f}, acc3 = {0.f, 0.f, 0.f, 0.f};

// Paired k-steps p: one b128 per col-tile feeds MFMA kk=2p (aE) and 2p+1 (aO).
#define MFMA_P(P_, aE, aO)                                                     \
    {                                                                          \
        const unsigned char* bb = bsp + ((P_) * 4 + lg) * 1024 + lr * 16;      \
        ll2 q0 = *reinterpret_cast<const ll2*>(bb);                            \
        ll2 q1 = *reinterpret_cast<const ll2*>(bb + 256);                      \
        ll2 q2 = *reinterpret_cast<const ll2*>(bb + 512);                      \
        ll2 q3 = *reinterpret_cast<const ll2*>(bb + 768);                      \
        acc0 = __builtin_amdgcn_mfma_f32_16x16x32_fp8_fp8(aE, q0[0], acc0, 0, 0, 0); \
        acc1 = __builtin_amdgcn_mfma_f32_16x16x32_fp8_fp8(aE, q1[0], acc1, 0, 0, 0); \
        acc2 = __builtin_amdgcn_mfma_f32_16x16x32_fp8_fp8(aE, q2[0], acc2, 0, 0, 0); \
        acc3 = __builtin_amdgcn_mfma_f32_16x16x32_fp8_fp8(aE, q3[0], acc3, 0, 0, 0); \
        acc0 = __builtin_amdgcn_mfma_f32_16x16x32_fp8_fp8(aO, q0[1], acc0, 0, 0, 0); \
        acc1 = __builtin_amdgcn_mfma_f32_16x16x32_fp8_fp8(aO, q1[1], acc1, 0, 0, 0); \
        acc2 = __builtin_amdgcn_mfma_f32_16x16x32_fp8_fp8(aO, q2[1], acc2, 0, 0, 0); \
        acc3 = __builtin_amdgcn_mfma_f32_16x16x32_fp8_fp8(aO, q3[1], acc3, 0, 0, 0); \
    }

#define FOLD_CT(accv, CT)                                                      \
    {                                                                          \
        const float pnv = pn_s[s * SC + (CT) * 16 + lr];                       \
        const int   ci  = s * SC + (CT) * 16 + lr;                             \
        float d;                                                               \
        d = fmaf(-DFACT, accv[0], pnv);                                        \
        if (d < bv0) { bv0 = d; bi0 = ci; }                                    \
        d = fmaf(-DFACT, accv[1], pnv);                                        \
        if (d < bv1) { bv1 = d; bi1 = ci; }                                    \
        d = fmaf(-DFACT, accv[2], pnv);                                        \
        if (d < bv2) { bv2 = d; bi2 = ci; }                                    \
        d = fmaf(-DFACT, accv[3], pnv);                                        \
        if (d < bv3) { bv3 = d; bi3 = ci; }                                    \
        accv = (f32x4){0.f, 0.f, 0.f, 0.f};                                    \
    }

    for (int s = 0; s < NS; ++s) {
        __builtin_amdgcn_s_barrier();            // all waves done with buf s&1
        if (s + 1 < NS) {
            STAGE(s + 1, (s + 1) & 1);           // issue next stage's 4 loads
            asm volatile("s_waitcnt vmcnt(4)" ::: "memory");  // stage s landed
        } else {
            asm volatile("s_waitcnt vmcnt(0)" ::: "memory");
        }
        __builtin_amdgcn_s_barrier();
        __builtin_amdgcn_sched_barrier(0);

        const unsigned char* bsp = Bs[s & 1];
        MFMA_P(0, a0,  a1)  MFMA_P(1, a2,  a3)
        MFMA_P(2, a4,  a5)  MFMA_P(3, a6,  a7)
        MFMA_P(4, a8,  a9)  MFMA_P(5, a10, a11)
        MFMA_P(6, a12, a13) MFMA_P(7, a14, a15)

        FOLD_CT(acc0, 0) FOLD_CT(acc1, 1) FOLD_CT(acc2, 2) FOLD_CT(acc3, 3)
    }
#undef MFMA_P
#undef FOLD_CT

    // ---- wave-private argmin across the 16 col-holding lanes ----
#define MERGE(bv, bi, SLOT)                                                    \
    {                                                                          \
        _Pragma("unroll")                                                      \
        for (int m = 1; m < 16; m <<= 1) {                                     \
            float ov = __shfl_xor(bv, m);                                      \
            int   oi = __shfl_xor(bi, m);                                      \
            if (ov < bv || (ov == bv && oi < bi)) { bv = ov; bi = oi; }        \
        }                                                                      \
        if (lr == 0) idx_s[wid * 16 + lg * 4 + (SLOT)] = bi;                   \
    }
    MERGE(bv0, bi0, 0) MERGE(bv1, bi1, 1) MERGE(bv2, bi2, 2) MERGE(bv3, bi3, 3)
#undef MERGE

    // loss partial: best dists (lr==0 lanes) + ||x||^2 (all lanes)
    float lcl = xsq + (lr == 0 ? bv0 + bv1 + bv2 + bv3 : 0.f);
#pragma unroll
    for (int o = 32; o > 0; o >>= 1) lcl += __shfl_down(lcl, o);
    if (lane == 0) wls[wid] = lcl;
    __syncthreads();
    if (tid == 0) {
        double t = 0.0;
#pragma unroll
        for (int w = 0; w < 8; ++w) t += (double)wls[w];
        atomicAdd(lsum, t);
    }

    // ---- epilogue: out[r] = P[idx[r]] (P L2-hot; stores nontemporal) ----
#pragma unroll 4
    for (int i = 0; i < 32; ++i) {
        int q = tid + i * 512;            // 128 rows x 128 float4
        int r = q >> 7, f4 = q & 127;
        f32x4 pv = *reinterpret_cast<const f32x4*>(
            P + (size_t)idx_s[r] * DIM + f4 * 4);
        __builtin_nontemporal_store(
            pv, reinterpret_cast<f32x4*>(out + (row0 + r) * DIM + f4 * 4));
    }
}

__global__ void finalize_kernel(const double* __restrict__ lsum,
                                float* __restrict__ out_loss) {
    out_loss[0] = (float)(1.25 * lsum[0] / ((double)N_ROWS * (double)DIM));
}

extern "C" void kernel_launch(void* const* d_in, const int* in_sizes, int n_in,
                              void* d_out, int out_size, void* d_ws, size_t ws_size,
                              hipStream_t stream) {
    const float* X = (const float*)d_in[0];
    const float* P = (const float*)d_in[1];
    float* out = (float*)d_out;

    // ws: [0,8) lsum; [256,+2K) pn; [4096,+256K) Pq fp8 (paired layout)
    double*        lsum = (double*)d_ws;
    float*         pn   = (float*)((char*)d_ws + 256);
    unsigned char* Pq   = (unsigned char*)d_ws + 4096;

    (void)hipMemsetAsync(d_ws, 0, 64, stream);
    prep_kernel<<<KP, 64, 0, stream>>>(P, pn, Pq);
    vq_kernel<<<N_ROWS / BM, 512, 0, stream>>>(X, P, Pq, pn, out, lsum);
    finalize_kernel<<<1, 1, 0, stream>>>(lsum, out + (size_t)N_ROWS * DIM);
    (void)hipMemcpyAsync(out + (size_t)N_ROWS * DIM + 1, P,
                         (size_t)KP * DIM * sizeof(float),
                         hipMemcpyDeviceToDevice, stream);
}